// Round 7
// baseline (978.329 us; speedup 1.0000x reference)
//
#include <hip/hip_runtime.h>
#include <math.h>

#define N_NODES 100000
#define N_EDGES 3200000
#define D_NODE 22
#define HIDDEN 32

// scan geometry: 98 blocks * 1024 elements = 100352 >= N_NODES
#define SCAN_ELEMS 1024
#define SCAN_NB    98
#define N_PAD      (SCAN_NB * SCAN_ELEMS)

#define EDGE_NB    (N_EDGES / 256)   // 12500 exact
#define NODE_NB    ((N_NODES + 255) / 256)

typedef unsigned int uint_v4 __attribute__((ext_vector_type(4)));
typedef float        f32_v2  __attribute__((ext_vector_type(2)));

__device__ __forceinline__ float softplus_f(float v) {
    return fmaxf(v, 0.0f) + log1pf(expf(-fabsf(v)));
}

// manual RNE float->bf16
__device__ __forceinline__ unsigned short f2bf(float f) {
    unsigned int u = __float_as_uint(f);
    unsigned int r = (u + 0x7fffu + ((u >> 16) & 1u)) >> 16;
    return (unsigned short)r;
}
__device__ __forceinline__ unsigned int pk2(float a, float b) {
    return (unsigned int)f2bf(a) | ((unsigned int)f2bf(b) << 16);
}
__device__ __forceinline__ float bflo(unsigned int w) {
    return __uint_as_float(w << 16);
}
__device__ __forceinline__ float bfhi(unsigned int w) {
    return __uint_as_float(w & 0xffff0000u);
}

// ---- CSR build ------------------------------------------------------------

__global__ __launch_bounds__(256) void count_kernel(
    const int* __restrict__ ei, int* __restrict__ counts)
{
    int e = blockIdx.x * blockDim.x + threadIdx.x;
    if (e < N_EDGES) atomicAdd(&counts[ei[e]], 1);
}

__global__ __launch_bounds__(256) void scan_part(
    const int* __restrict__ counts, int* __restrict__ offsets,
    int* __restrict__ bsums)
{
    __shared__ int lds[256];
    const int tid = threadIdx.x;
    const int base = blockIdx.x * SCAN_ELEMS + tid * 4;

    int v0 = (base + 0 < N_NODES) ? counts[base + 0] : 0;
    int v1 = (base + 1 < N_NODES) ? counts[base + 1] : 0;
    int v2 = (base + 2 < N_NODES) ? counts[base + 2] : 0;
    int v3 = (base + 3 < N_NODES) ? counts[base + 3] : 0;
    const int s = v0 + v1 + v2 + v3;

    lds[tid] = s;
    __syncthreads();
    for (int off = 1; off < 256; off <<= 1) {
        int t = (tid >= off) ? lds[tid - off] : 0;
        __syncthreads();
        lds[tid] += t;
        __syncthreads();
    }
    const int excl = lds[tid] - s;

    offsets[base + 0] = excl;
    offsets[base + 1] = excl + v0;
    offsets[base + 2] = excl + v0 + v1;
    offsets[base + 3] = excl + v0 + v1 + v2;

    if (tid == 0) bsums[blockIdx.x] = lds[255];
}

__global__ __launch_bounds__(128) void scan_sums(int* __restrict__ bsums)
{
    __shared__ int lds[128];
    const int tid = threadIdx.x;
    int v = (tid < SCAN_NB) ? bsums[tid] : 0;
    lds[tid] = v;
    __syncthreads();
    for (int off = 1; off < 128; off <<= 1) {
        int t = (tid >= off) ? lds[tid - off] : 0;
        __syncthreads();
        lds[tid] += t;
        __syncthreads();
    }
    if (tid < SCAN_NB) bsums[tid] = lds[tid] - v;
}

// finalize offsets and copy into cursor (cursor aliases the dead counts buf)
__global__ __launch_bounds__(256) void scan_add_cursor(
    int* __restrict__ offsets, const int* __restrict__ bsums,
    int* __restrict__ cursor)
{
    const int add = bsums[blockIdx.x];
    const int base = blockIdx.x * SCAN_ELEMS + threadIdx.x * 4;
#pragma unroll
    for (int q = 0; q < 4; ++q) {
        const int o = offsets[base + q] + add;
        offsets[base + q] = o;
        cursor[base + q]  = o;
    }
}

// atomic-cursor fill: edge_list[pos] = e (order within a node arbitrary)
__global__ __launch_bounds__(256) void fill_kernel(
    const int* __restrict__ ei, int* __restrict__ cursor,
    int* __restrict__ edge_list)
{
    int e = blockIdx.x * blockDim.x + threadIdx.x;
    if (e < N_EDGES) {
        int pos = atomicAdd(&cursor[ei[e]], 1);
        edge_list[pos] = e;
    }
}

// ---- per-node precompute: u = x @ W1[0:22], v = x @ W1[22:44]  (bf16 out) -
__global__ __launch_bounds__(256) void uv_kernel(
    const float* __restrict__ x, const float* __restrict__ W1,
    unsigned short* __restrict__ u, unsigned short* __restrict__ v)
{
    const int n = blockIdx.x * blockDim.x + threadIdx.x;
    if (n >= N_NODES) return;

    float a[D_NODE];
    const float2* xp = reinterpret_cast<const float2*>(x + (size_t)n * D_NODE);
#pragma unroll
    for (int q = 0; q < 11; ++q) {
        float2 t = xp[q];
        a[2 * q] = t.x; a[2 * q + 1] = t.y;
    }

    float uu[HIDDEN], vv[HIDDEN];
#pragma unroll
    for (int h = 0; h < HIDDEN; ++h) { uu[h] = 0.0f; vv[h] = 0.0f; }
#pragma unroll
    for (int k = 0; k < D_NODE; ++k) {
        const float t = a[k];
#pragma unroll
        for (int h = 0; h < HIDDEN; ++h) {
            uu[h] = fmaf(t, W1[k * HIDDEN + h], uu[h]);
            vv[h] = fmaf(t, W1[(D_NODE + k) * HIDDEN + h], vv[h]);
        }
    }

    uint_v4 U[4], V[4];
#pragma unroll
    for (int qq = 0; qq < 4; ++qq) {
        U[qq][0] = pk2(uu[8 * qq + 0], uu[8 * qq + 1]);
        U[qq][1] = pk2(uu[8 * qq + 2], uu[8 * qq + 3]);
        U[qq][2] = pk2(uu[8 * qq + 4], uu[8 * qq + 5]);
        U[qq][3] = pk2(uu[8 * qq + 6], uu[8 * qq + 7]);
        V[qq][0] = pk2(vv[8 * qq + 0], vv[8 * qq + 1]);
        V[qq][1] = pk2(vv[8 * qq + 2], vv[8 * qq + 3]);
        V[qq][2] = pk2(vv[8 * qq + 4], vv[8 * qq + 5]);
        V[qq][3] = pk2(vv[8 * qq + 6], vv[8 * qq + 7]);
    }
    uint_v4* up = reinterpret_cast<uint_v4*>(u + (size_t)n * HIDDEN);
    uint_v4* vp = reinterpret_cast<uint_v4*>(v + (size_t)n * HIDDEN);
#pragma unroll
    for (int qq = 0; qq < 4; ++qq) { up[qq] = U[qq]; vp[qq] = V[qq]; }
}

// ---- pass A: NATURAL-order per-edge hid = relu(u[src]+v[dst]+ea@W1c+b1)
//      -> coalesced streaming store of hid_nat[e] (64B bf16 row). No RMW. --
__global__ __launch_bounds__(256) void edge_hid_nat(
    const int*   __restrict__ ei,
    const float* __restrict__ ea,
    const unsigned short* __restrict__ u,
    const unsigned short* __restrict__ v,
    const float* __restrict__ W1,       // rows 44..65 (W1c)
    const float* __restrict__ b1,
    unsigned short* __restrict__ hid_nat)
{
    const int e = blockIdx.x * blockDim.x + threadIdx.x;

    const int src = ei[e];
    const int dst = ei[N_EDGES + e];

    // issue the two 64B gathers early (L2-resident 6.4MB tables)
    const uint_v4* up = reinterpret_cast<const uint_v4*>(u + (size_t)src * HIDDEN);
    const uint_v4* vp = reinterpret_cast<const uint_v4*>(v + (size_t)dst * HIDDEN);
    uint_v4 U0 = up[0], U1 = up[1], U2 = up[2], U3 = up[3];
    uint_v4 V0 = vp[0], V1 = vp[1], V2 = vp[2], V3 = vp[3];

    // ea row (88B, 8B-aligned), nontemporal: don't thrash u/v out of L2
    float a[D_NODE];
    const f32_v2* epp = reinterpret_cast<const f32_v2*>(ea + (size_t)e * D_NODE);
#pragma unroll
    for (int q = 0; q < 11; ++q) {
        f32_v2 t = __builtin_nontemporal_load(epp + q);
        a[2 * q] = t[0]; a[2 * q + 1] = t[1];
    }

    // w = ea @ W1c + b1   (W1c wave-uniform -> SGPR stream)
    float w[HIDDEN];
#pragma unroll
    for (int h = 0; h < HIDDEN; ++h) w[h] = b1[h];
#pragma unroll
    for (int k = 0; k < D_NODE; ++k) {
        const float t = a[k];
#pragma unroll
        for (int h = 0; h < HIDDEN; ++h)
            w[h] = fmaf(t, W1[(2 * D_NODE + k) * HIDDEN + h], w[h]);
    }

    const unsigned int uw[16] = {U0[0], U0[1], U0[2], U0[3], U1[0], U1[1], U1[2], U1[3],
                                 U2[0], U2[1], U2[2], U2[3], U3[0], U3[1], U3[2], U3[3]};
    const unsigned int vw[16] = {V0[0], V0[1], V0[2], V0[3], V1[0], V1[1], V1[2], V1[3],
                                 V2[0], V2[1], V2[2], V2[3], V3[0], V3[1], V3[2], V3[3]};

    unsigned int ow[16];
#pragma unroll
    for (int d = 0; d < 16; ++d) {
        const float h0 = fmaxf(bflo(uw[d]) + bflo(vw[d]) + w[2 * d],     0.0f);
        const float h1 = fmaxf(bfhi(uw[d]) + bfhi(vw[d]) + w[2 * d + 1], 0.0f);
        ow[d] = pk2(h0, h1);
    }

    // coalesced streaming store (consecutive e -> contiguous lines)
    uint_v4* dp = reinterpret_cast<uint_v4*>(hid_nat + (size_t)e * HIDDEN);
    uint_v4 q0 = {ow[0], ow[1], ow[2], ow[3]};
    uint_v4 q1 = {ow[4], ow[5], ow[6], ow[7]};
    uint_v4 q2 = {ow[8], ow[9], ow[10], ow[11]};
    uint_v4 q3 = {ow[12], ow[13], ow[14], ow[15]};
    __builtin_nontemporal_store(q0, dp + 0);
    __builtin_nontemporal_store(q1, dp + 1);
    __builtin_nontemporal_store(q2, dp + 2);
    __builtin_nontemporal_store(q3, dp + 3);
}

// ---- pass B: CSR-order gather of hid_nat + segmented reduction -> H -------
__global__ __launch_bounds__(256) void reduce_gather(
    const unsigned short* __restrict__ hid_nat,
    const int* __restrict__ edge_list,
    const int* __restrict__ ei,
    float* __restrict__ H)
{
    __shared__ float lmsg[256][33];
    __shared__ int   lsrc[256];
    __shared__ int   lstart[257];
    __shared__ unsigned long long lmask[4];

    const int tid = threadIdx.x;
    const int p = blockIdx.x * 256 + tid;

    const int e = edge_list[p];          // coalesced
    const int src = ei[e];               // 4B gather (12.8MB, L2/L3)

    // 64B gather of this edge's hid row (random over 205MB, mostly L3)
    const uint_v4* mr = reinterpret_cast<const uint_v4*>(hid_nat + (size_t)e * HIDDEN);
    uint_v4 m0 = __builtin_nontemporal_load(mr + 0);
    uint_v4 m1 = __builtin_nontemporal_load(mr + 1);
    uint_v4 m2 = __builtin_nontemporal_load(mr + 2);
    uint_v4 m3 = __builtin_nontemporal_load(mr + 3);
    unsigned int ww[16] = {m0[0], m0[1], m0[2], m0[3], m1[0], m1[1], m1[2], m1[3],
                           m2[0], m2[1], m2[2], m2[3], m3[0], m3[1], m3[2], m3[3]};
#pragma unroll
    for (int d = 0; d < 16; ++d) {
        lmsg[tid][2 * d]     = bflo(ww[d]);
        lmsg[tid][2 * d + 1] = bfhi(ww[d]);
    }
    lsrc[tid] = src;
    __syncthreads();

    const bool head = (tid == 0) || (lsrc[tid] != lsrc[tid - 1]);
    const unsigned long long m = __ballot(head ? 1 : 0);
    const int wv = tid >> 6, lane = tid & 63;
    if (lane == 0) lmask[wv] = m;
    __syncthreads();

    const int nseg = __popcll(lmask[0]) + __popcll(lmask[1]) +
                     __popcll(lmask[2]) + __popcll(lmask[3]);
    if (head) {
        int sid = 0;
        for (int w = 0; w < 4; ++w)
            if (w < wv) sid += __popcll(lmask[w]);
        const unsigned long long below =
            (lane == 0) ? 0ULL : (lmask[wv] & ((1ULL << lane) - 1ULL));
        sid += __popcll(below);
        lstart[sid] = tid;
    }
    if (tid == 0) lstart[nseg] = 256;
    __syncthreads();

    for (int item = tid; item < nseg * HIDDEN; item += 256) {
        const int s = item >> 5;
        const int c = item & 31;
        const int st = lstart[s];
        const int en = lstart[s + 1];
        float sum = 0.0f;
        for (int r = st; r < en; ++r) sum += lmsg[r][c];
        const int node = lsrc[st];
        float* dstp = H + (size_t)node * HIDDEN + c;
        if (s == 0 || s == nseg - 1) atomicAdd(dstp, sum);
        else *dstp = sum;
    }
}

// ---- pass C: per node  agg = H@W2 + deg*b2 ; heads -------------------------
__global__ __launch_bounds__(256) void node_out_kernel(
    const float* __restrict__ x,
    const float* __restrict__ H,
    const int*   __restrict__ offsets,   // deg = offsets[n+1]-offsets[n]
    const float* __restrict__ W2,  const float* __restrict__ b2,
    const float* __restrict__ Wmu,  const float* __restrict__ bmu,
    const float* __restrict__ Wsig, const float* __restrict__ bsig,
    const float* __restrict__ Wconc,const float* __restrict__ bconc,
    float*       __restrict__ out)
{
    const int n = blockIdx.x * blockDim.x + threadIdx.x;
    if (n >= N_NODES) return;

    const float degf = (float)(offsets[n + 1] - offsets[n]);

    float hr[HIDDEN];
    const float4* hp = reinterpret_cast<const float4*>(H + (size_t)n * HIDDEN);
#pragma unroll
    for (int q = 0; q < 8; ++q) {
        float4 t = hp[q];
        hr[4 * q + 0] = t.x; hr[4 * q + 1] = t.y;
        hr[4 * q + 2] = t.z; hr[4 * q + 3] = t.w;
    }

    float agg[HIDDEN];
#pragma unroll
    for (int h = 0; h < HIDDEN; ++h) agg[h] = degf * b2[h];
#pragma unroll
    for (int k = 0; k < HIDDEN; ++k) {
        const float t = hr[k];
#pragma unroll
        for (int h = 0; h < HIDDEN; ++h)
            agg[h] = fmaf(t, W2[k * HIDDEN + h], agg[h]);
    }

    float a[D_NODE];
    const float2* xp = reinterpret_cast<const float2*>(x + (size_t)n * D_NODE);
#pragma unroll
    for (int q = 0; q < 11; ++q) {
        float2 t = xp[q];
        a[2 * q] = t.x; a[2 * q + 1] = t.y;
    }

    float mu = bmu[0], sg = bsig[0], al = bconc[0];
#pragma unroll
    for (int k = 0; k < D_NODE; ++k) {
        const float t = a[k];
        mu = fmaf(t, Wmu[k],   mu);
        sg = fmaf(t, Wsig[k],  sg);
        al = fmaf(t, Wconc[k], al);
    }
#pragma unroll
    for (int k = 0; k < HIDDEN; ++k) {
        const float t = agg[k];
        mu = fmaf(t, Wmu[D_NODE + k],   mu);
        sg = fmaf(t, Wsig[D_NODE + k],  sg);
        al = fmaf(t, Wconc[D_NODE + k], al);
    }

    out[n]               = softplus_f(mu);
    out[N_NODES + n]     = softplus_f(sg);
    out[2 * N_NODES + n] = softplus_f(al);
}

// ---- fallback: round-3 proven fused path ----------------------------------

__global__ __launch_bounds__(256) void edge_mlp_reduce(
    const float* __restrict__ x,
    const int*   __restrict__ edge_index,
    const float* __restrict__ edge_attr,
    const int*   __restrict__ edge_list,
    const float* __restrict__ W1,
    const float* __restrict__ b1,
    const float* __restrict__ W2,
    const float* __restrict__ b2,
    float*       __restrict__ agg)
{
    __shared__ float lmsg[256][33];
    __shared__ int   lsrc[256];
    __shared__ int   lstart[257];
    __shared__ unsigned long long lmask[4];

    const int tid = threadIdx.x;
    const int p = blockIdx.x * 256 + tid;

    const int e   = edge_list[p];
    const int src = edge_index[e];
    const int j   = edge_index[N_EDGES + e];

    const float* __restrict__ xi = x + (size_t)src * D_NODE;
    const float* __restrict__ xj = x + (size_t)j   * D_NODE;
    const float* __restrict__ ep = edge_attr + (size_t)e * D_NODE;

    float hid[HIDDEN];
#pragma unroll
    for (int h = 0; h < HIDDEN; ++h) hid[h] = b1[h];
#pragma unroll
    for (int k = 0; k < D_NODE; ++k) {
        const float t = xi[k];
#pragma unroll
        for (int h = 0; h < HIDDEN; ++h)
            hid[h] = fmaf(t, W1[k * HIDDEN + h], hid[h]);
    }
#pragma unroll
    for (int k = 0; k < D_NODE; ++k) {
        const float t = xj[k];
#pragma unroll
        for (int h = 0; h < HIDDEN; ++h)
            hid[h] = fmaf(t, W1[(D_NODE + k) * HIDDEN + h], hid[h]);
    }
#pragma unroll
    for (int k = 0; k < D_NODE; ++k) {
        const float t = ep[k];
#pragma unroll
        for (int h = 0; h < HIDDEN; ++h)
            hid[h] = fmaf(t, W1[(2 * D_NODE + k) * HIDDEN + h], hid[h]);
    }
#pragma unroll
    for (int h = 0; h < HIDDEN; ++h) hid[h] = fmaxf(hid[h], 0.0f);

    float msg[HIDDEN];
#pragma unroll
    for (int o = 0; o < HIDDEN; ++o) msg[o] = b2[o];
#pragma unroll
    for (int k = 0; k < HIDDEN; ++k) {
        const float t = hid[k];
#pragma unroll
        for (int o = 0; o < HIDDEN; ++o)
            msg[o] = fmaf(t, W2[k * HIDDEN + o], msg[o]);
    }

    lsrc[tid] = src;
#pragma unroll
    for (int o = 0; o < HIDDEN; ++o) lmsg[tid][o] = msg[o];
    __syncthreads();

    const bool head = (tid == 0) || (lsrc[tid] != lsrc[tid - 1]);
    const unsigned long long m = __ballot(head ? 1 : 0);
    const int wv = tid >> 6, lane = tid & 63;
    if (lane == 0) lmask[wv] = m;
    __syncthreads();

    const int nseg = __popcll(lmask[0]) + __popcll(lmask[1]) +
                     __popcll(lmask[2]) + __popcll(lmask[3]);
    if (head) {
        int sid = 0;
        for (int w = 0; w < 4; ++w)
            if (w < wv) sid += __popcll(lmask[w]);
        const unsigned long long below =
            (lane == 0) ? 0ULL : (lmask[wv] & ((1ULL << lane) - 1ULL));
        sid += __popcll(below);
        lstart[sid] = tid;
    }
    if (tid == 0) lstart[nseg] = 256;
    __syncthreads();

    for (int item = tid; item < nseg * HIDDEN; item += 256) {
        const int s = item >> 5;
        const int c = item & 31;
        const int st = lstart[s];
        const int en = lstart[s + 1];
        float sum = 0.0f;
        for (int r = st; r < en; ++r) sum += lmsg[r][c];
        const int node = lsrc[st];
        float* dstp = agg + (size_t)node * HIDDEN + c;
        if (s == 0 || s == nseg - 1) atomicAdd(dstp, sum);
        else *dstp = sum;
    }
}

__global__ __launch_bounds__(256) void node_head_kernel(
    const float* __restrict__ x,
    const float* __restrict__ agg,
    const float* __restrict__ Wmu,  const float* __restrict__ bmu,
    const float* __restrict__ Wsig, const float* __restrict__ bsig,
    const float* __restrict__ Wconc,const float* __restrict__ bconc,
    float*       __restrict__ out)
{
    int n = blockIdx.x * blockDim.x + threadIdx.x;
    if (n >= N_NODES) return;

    float mu = bmu[0], sg = bsig[0], al = bconc[0];

    const float* __restrict__ xp = x + (size_t)n * D_NODE;
#pragma unroll
    for (int k = 0; k < D_NODE; ++k) {
        const float t = xp[k];
        mu = fmaf(t, Wmu[k],   mu);
        sg = fmaf(t, Wsig[k],  sg);
        al = fmaf(t, Wconc[k], al);
    }
    const float* __restrict__ ap = agg + (size_t)n * HIDDEN;
#pragma unroll
    for (int k = 0; k < HIDDEN; ++k) {
        const float t = ap[k];
        mu = fmaf(t, Wmu[D_NODE + k],   mu);
        sg = fmaf(t, Wsig[D_NODE + k],  sg);
        al = fmaf(t, Wconc[D_NODE + k], al);
    }

    out[n]               = softplus_f(mu);
    out[N_NODES + n]     = softplus_f(sg);
    out[2 * N_NODES + n] = softplus_f(al);
}

// ---- launch ---------------------------------------------------------------

extern "C" void kernel_launch(void* const* d_in, const int* in_sizes, int n_in,
                              void* d_out, int out_size, void* d_ws, size_t ws_size,
                              hipStream_t stream) {
    const float* x     = (const float*)d_in[0];
    const int*   ei    = (const int*)  d_in[1];
    const float* ea    = (const float*)d_in[2];
    const float* W1    = (const float*)d_in[3];
    const float* b1    = (const float*)d_in[4];
    const float* W2    = (const float*)d_in[5];
    const float* b2    = (const float*)d_in[6];
    const float* Wmu   = (const float*)d_in[7];
    const float* bmu   = (const float*)d_in[8];
    const float* Wsig  = (const float*)d_in[9];
    const float* bsig  = (const float*)d_in[10];
    const float* Wconc = (const float*)d_in[11];
    const float* bconc = (const float*)d_in[12];

    float* out = (float*)d_out;

    // layout (4B words):
    //   counts/cursor[N_PAD] | offsets[N_PAD] | bsums[128] | edge_list[E] |
    //   u[N*32 bf16] v[N*32 bf16]  (== H[N*32 f32] overlaid, 12.8MB) |
    //   hid_nat[E*32 bf16] (204.8MB)
    int* counts  = (int*)d_ws;              // reused as cursor after scan
    int* offsets = counts + N_PAD;
    int* bsums   = offsets + N_PAD;
    int* edge_list = bsums + 128;
    unsigned short* u = (unsigned short*)(edge_list + N_EDGES);
    unsigned short* v = u + (size_t)N_NODES * HIDDEN;
    float* H          = (float*)u;          // overlays u|v after edge pass
    unsigned short* hid_nat = v + (size_t)N_NODES * HIDDEN;

    const size_t req =
        ((size_t)N_PAD * 2 + 128 + N_EDGES) * 4
        + (size_t)N_NODES * HIDDEN * 2 * 2        // u + v
        + (size_t)N_EDGES * HIDDEN * 2;           // hid_nat

    if (ws_size >= req) {
        (void)hipMemsetAsync(counts, 0, N_PAD * sizeof(int), stream);
        uv_kernel<<<NODE_NB, 256, 0, stream>>>(x, W1, u, v);
        count_kernel<<<EDGE_NB, 256, 0, stream>>>(ei, counts);
        scan_part<<<SCAN_NB, 256, 0, stream>>>(counts, offsets, bsums);
        scan_sums<<<1, 128, 0, stream>>>(bsums);
        scan_add_cursor<<<SCAN_NB, 256, 0, stream>>>(offsets, bsums, counts);
        fill_kernel<<<EDGE_NB, 256, 0, stream>>>(ei, counts, edge_list);

        edge_hid_nat<<<EDGE_NB, 256, 0, stream>>>(
            ei, ea, u, v, W1, b1, hid_nat);

        // u,v dead now; zero the same region as H
        (void)hipMemsetAsync(H, 0, (size_t)N_NODES * HIDDEN * sizeof(float), stream);
        reduce_gather<<<EDGE_NB, 256, 0, stream>>>(hid_nat, edge_list, ei, H);

        node_out_kernel<<<NODE_NB, 256, 0, stream>>>(
            x, H, offsets, W2, b2, Wmu, bmu, Wsig, bsig, Wconc, bconc, out);
    } else {
        // fallback: round-3 proven path (CSR build shared, fused VALU edge pass)
        float* agg_fb = (float*)u;   // 12.8MB region

        (void)hipMemsetAsync(counts, 0, N_PAD * sizeof(int), stream);
        count_kernel<<<EDGE_NB, 256, 0, stream>>>(ei, counts);
        scan_part<<<SCAN_NB, 256, 0, stream>>>(counts, offsets, bsums);
        scan_sums<<<1, 128, 0, stream>>>(bsums);
        scan_add_cursor<<<SCAN_NB, 256, 0, stream>>>(offsets, bsums, counts);
        fill_kernel<<<EDGE_NB, 256, 0, stream>>>(ei, counts, edge_list);
        (void)hipMemsetAsync(agg_fb, 0, (size_t)N_NODES * HIDDEN * sizeof(float), stream);
        edge_mlp_reduce<<<EDGE_NB, 256, 0, stream>>>(
            x, ei, ea, edge_list, W1, b1, W2, b2, agg_fb);
        node_head_kernel<<<NODE_NB, 256, 0, stream>>>(
            x, agg_fb, Wmu, bmu, Wsig, bsig, Wconc, bconc, out);
    }
}

// Round 8
// 515.605 us; speedup vs baseline: 1.8974x; 1.8974x over previous
//
#include <hip/hip_runtime.h>
#include <math.h>

#define N_NODES 100000
#define N_EDGES 3200000
#define D_NODE 22
#define HIDDEN 32

// scan geometry: 98 blocks * 1024 elements = 100352 >= N_NODES
#define SCAN_ELEMS 1024
#define SCAN_NB    98
#define N_PAD      (SCAN_NB * SCAN_ELEMS)

#define EDGE_NB    (N_EDGES / 256)   // 12500 exact
#define NODE_NB    ((N_NODES + 255) / 256)

typedef unsigned int uint_v4 __attribute__((ext_vector_type(4)));

__device__ __forceinline__ float softplus_f(float v) {
    return fmaxf(v, 0.0f) + log1pf(expf(-fabsf(v)));
}

// manual RNE float->bf16
__device__ __forceinline__ unsigned short f2bf(float f) {
    unsigned int u = __float_as_uint(f);
    unsigned int r = (u + 0x7fffu + ((u >> 16) & 1u)) >> 16;
    return (unsigned short)r;
}
__device__ __forceinline__ unsigned int pk2(float a, float b) {
    return (unsigned int)f2bf(a) | ((unsigned int)f2bf(b) << 16);
}
__device__ __forceinline__ float bflo(unsigned int w) {
    return __uint_as_float(w << 16);
}
__device__ __forceinline__ float bfhi(unsigned int w) {
    return __uint_as_float(w & 0xffff0000u);
}

// ---- CSR build (round-3 proven) -------------------------------------------

__global__ __launch_bounds__(256) void count_rank_kernel(
    const int* __restrict__ ei, int* __restrict__ counts,
    int* __restrict__ rank)
{
    int e = blockIdx.x * blockDim.x + threadIdx.x;
    if (e < N_EDGES) rank[e] = atomicAdd(&counts[ei[e]], 1);
}

__global__ __launch_bounds__(256) void scan_part(
    const int* __restrict__ counts, int* __restrict__ offsets,
    int* __restrict__ bsums)
{
    __shared__ int lds[256];
    const int tid = threadIdx.x;
    const int base = blockIdx.x * SCAN_ELEMS + tid * 4;

    int v0 = (base + 0 < N_NODES) ? counts[base + 0] : 0;
    int v1 = (base + 1 < N_NODES) ? counts[base + 1] : 0;
    int v2 = (base + 2 < N_NODES) ? counts[base + 2] : 0;
    int v3 = (base + 3 < N_NODES) ? counts[base + 3] : 0;
    const int s = v0 + v1 + v2 + v3;

    lds[tid] = s;
    __syncthreads();
    for (int off = 1; off < 256; off <<= 1) {
        int t = (tid >= off) ? lds[tid - off] : 0;
        __syncthreads();
        lds[tid] += t;
        __syncthreads();
    }
    const int excl = lds[tid] - s;

    offsets[base + 0] = excl;
    offsets[base + 1] = excl + v0;
    offsets[base + 2] = excl + v0 + v1;
    offsets[base + 3] = excl + v0 + v1 + v2;

    if (tid == 0) bsums[blockIdx.x] = lds[255];
}

__global__ __launch_bounds__(128) void scan_sums(int* __restrict__ bsums)
{
    __shared__ int lds[128];
    const int tid = threadIdx.x;
    int v = (tid < SCAN_NB) ? bsums[tid] : 0;
    lds[tid] = v;
    __syncthreads();
    for (int off = 1; off < 128; off <<= 1) {
        int t = (tid >= off) ? lds[tid - off] : 0;
        __syncthreads();
        lds[tid] += t;
        __syncthreads();
    }
    if (tid < SCAN_NB) bsums[tid] = lds[tid] - v;
}

__global__ __launch_bounds__(256) void scan_add(
    int* __restrict__ offsets, const int* __restrict__ bsums)
{
    const int add = bsums[blockIdx.x];
    const int base = blockIdx.x * SCAN_ELEMS + threadIdx.x * 4;
    offsets[base + 0] += add;
    offsets[base + 1] += add;
    offsets[base + 2] += add;
    offsets[base + 3] += add;
}

// atomic-free fill: pos = start[src] + rank[e]
__global__ __launch_bounds__(256) void fill_kernel(
    const int* __restrict__ ei, const int* __restrict__ offsets,
    const int* __restrict__ rank, int* __restrict__ edge_list)
{
    int e = blockIdx.x * blockDim.x + threadIdx.x;
    if (e < N_EDGES)
        edge_list[offsets[ei[e]] + rank[e]] = e;
}

// ---- per-node precompute: u = x @ W1[0:22], v = x @ W1[22:44]  (bf16) -----
__global__ __launch_bounds__(256) void uv_kernel(
    const float* __restrict__ x, const float* __restrict__ W1,
    unsigned short* __restrict__ u, unsigned short* __restrict__ v)
{
    const int n = blockIdx.x * blockDim.x + threadIdx.x;
    if (n >= N_NODES) return;

    float a[D_NODE];
    const float2* xp = reinterpret_cast<const float2*>(x + (size_t)n * D_NODE);
#pragma unroll
    for (int q = 0; q < 11; ++q) {
        float2 t = xp[q];
        a[2 * q] = t.x; a[2 * q + 1] = t.y;
    }

    float uu[HIDDEN], vv[HIDDEN];
#pragma unroll
    for (int h = 0; h < HIDDEN; ++h) { uu[h] = 0.0f; vv[h] = 0.0f; }
#pragma unroll
    for (int k = 0; k < D_NODE; ++k) {
        const float t = a[k];
#pragma unroll
        for (int h = 0; h < HIDDEN; ++h) {
            uu[h] = fmaf(t, W1[k * HIDDEN + h], uu[h]);
            vv[h] = fmaf(t, W1[(D_NODE + k) * HIDDEN + h], vv[h]);
        }
    }

    uint_v4 U[4], V[4];
#pragma unroll
    for (int qq = 0; qq < 4; ++qq) {
        U[qq][0] = pk2(uu[8 * qq + 0], uu[8 * qq + 1]);
        U[qq][1] = pk2(uu[8 * qq + 2], uu[8 * qq + 3]);
        U[qq][2] = pk2(uu[8 * qq + 4], uu[8 * qq + 5]);
        U[qq][3] = pk2(uu[8 * qq + 6], uu[8 * qq + 7]);
        V[qq][0] = pk2(vv[8 * qq + 0], vv[8 * qq + 1]);
        V[qq][1] = pk2(vv[8 * qq + 2], vv[8 * qq + 3]);
        V[qq][2] = pk2(vv[8 * qq + 4], vv[8 * qq + 5]);
        V[qq][3] = pk2(vv[8 * qq + 6], vv[8 * qq + 7]);
    }
    uint_v4* up = reinterpret_cast<uint_v4*>(u + (size_t)n * HIDDEN);
    uint_v4* vp = reinterpret_cast<uint_v4*>(v + (size_t)n * HIDDEN);
#pragma unroll
    for (int qq = 0; qq < 4; ++qq) { up[qq] = U[qq]; vp[qq] = V[qq]; }
}

// ---- fused edge pass (round-3 structure + u/v/w algebra) ------------------
// One lane per CSR position. hid = relu(u[src] + v[dst] + ea@W1c + b1);
// segmented-reduce hid by src into H (interior nodes: plain store).
__global__ __launch_bounds__(256) void edge_fused_reduce(
    const int*   __restrict__ ei,
    const float* __restrict__ ea,
    const int*   __restrict__ edge_list,
    const unsigned short* __restrict__ u,
    const unsigned short* __restrict__ v,
    const float* __restrict__ W1,       // rows 44..65 (W1c)
    const float* __restrict__ b1,
    float*       __restrict__ H)
{
    __shared__ float lmsg[256][33];
    __shared__ int   lsrc[256];
    __shared__ int   lstart[257];
    __shared__ unsigned long long lmask[4];

    const int tid = threadIdx.x;
    const int p = blockIdx.x * 256 + tid;

    const int e   = edge_list[p];        // coalesced
    const int src = ei[e];               // random 4B (L2/L3)
    const int dst = ei[N_EDGES + e];     // random 4B (L2/L3)

    // issue u/v gathers early; src is CSR-sorted -> u reads nearly sequential
    const uint_v4* up = reinterpret_cast<const uint_v4*>(u + (size_t)src * HIDDEN);
    const uint_v4* vp = reinterpret_cast<const uint_v4*>(v + (size_t)dst * HIDDEN);
    uint_v4 U0 = up[0], U1 = up[1], U2 = up[2], U3 = up[3];
    uint_v4 V0 = vp[0], V1 = vp[1], V2 = vp[2], V3 = vp[3];

    // ea row (88B random gather; unavoidable in CSR order)
    float a[D_NODE];
    const float2* epp = reinterpret_cast<const float2*>(ea + (size_t)e * D_NODE);
#pragma unroll
    for (int q = 0; q < 11; ++q) {
        float2 t = epp[q];
        a[2 * q] = t.x; a[2 * q + 1] = t.y;
    }

    // w = ea @ W1c + b1   (704 FMA, wave-uniform weights -> SGPR stream)
    float w[HIDDEN];
#pragma unroll
    for (int h = 0; h < HIDDEN; ++h) w[h] = b1[h];
#pragma unroll
    for (int k = 0; k < D_NODE; ++k) {
        const float t = a[k];
#pragma unroll
        for (int h = 0; h < HIDDEN; ++h)
            w[h] = fmaf(t, W1[(2 * D_NODE + k) * HIDDEN + h], w[h]);
    }

    const unsigned int uw[16] = {U0[0], U0[1], U0[2], U0[3], U1[0], U1[1], U1[2], U1[3],
                                 U2[0], U2[1], U2[2], U2[3], U3[0], U3[1], U3[2], U3[3]};
    const unsigned int vw[16] = {V0[0], V0[1], V0[2], V0[3], V1[0], V1[1], V1[2], V1[3],
                                 V2[0], V2[1], V2[2], V2[3], V3[0], V3[1], V3[2], V3[3]};

    // hid = relu(u + v + w) straight into LDS
#pragma unroll
    for (int d = 0; d < 16; ++d) {
        lmsg[tid][2 * d]     = fmaxf(bflo(uw[d]) + bflo(vw[d]) + w[2 * d],     0.0f);
        lmsg[tid][2 * d + 1] = fmaxf(bfhi(uw[d]) + bfhi(vw[d]) + w[2 * d + 1], 0.0f);
    }
    lsrc[tid] = src;
    __syncthreads();

    // ---- segmented reduction by src (round-3 verified) ----
    const bool head = (tid == 0) || (lsrc[tid] != lsrc[tid - 1]);
    const unsigned long long m = __ballot(head ? 1 : 0);
    const int wv = tid >> 6, lane = tid & 63;
    if (lane == 0) lmask[wv] = m;
    __syncthreads();

    const int nseg = __popcll(lmask[0]) + __popcll(lmask[1]) +
                     __popcll(lmask[2]) + __popcll(lmask[3]);
    if (head) {
        int sid = 0;
        for (int ww2 = 0; ww2 < 4; ++ww2)
            if (ww2 < wv) sid += __popcll(lmask[ww2]);
        const unsigned long long below =
            (lane == 0) ? 0ULL : (lmask[wv] & ((1ULL << lane) - 1ULL));
        sid += __popcll(below);
        lstart[sid] = tid;
    }
    if (tid == 0) lstart[nseg] = 256;
    __syncthreads();

    for (int item = tid; item < nseg * HIDDEN; item += 256) {
        const int s = item >> 5;
        const int c = item & 31;
        const int st = lstart[s];
        const int en = lstart[s + 1];
        float sum = 0.0f;
        for (int r = st; r < en; ++r) sum += lmsg[r][c];
        const int node = lsrc[st];
        float* dstp = H + (size_t)node * HIDDEN + c;
        if (s == 0 || s == nseg - 1) atomicAdd(dstp, sum);
        else *dstp = sum;
    }
}

// ---- per node: agg = H@W2 + deg*b2 ; heads --------------------------------
__global__ __launch_bounds__(256) void node_out_kernel(
    const float* __restrict__ x,
    const float* __restrict__ H,
    const int*   __restrict__ counts,     // deg
    const float* __restrict__ W2,  const float* __restrict__ b2,
    const float* __restrict__ Wmu,  const float* __restrict__ bmu,
    const float* __restrict__ Wsig, const float* __restrict__ bsig,
    const float* __restrict__ Wconc,const float* __restrict__ bconc,
    float*       __restrict__ out)
{
    const int n = blockIdx.x * blockDim.x + threadIdx.x;
    if (n >= N_NODES) return;

    const float degf = (float)counts[n];

    float hr[HIDDEN];
    const float4* hp = reinterpret_cast<const float4*>(H + (size_t)n * HIDDEN);
#pragma unroll
    for (int q = 0; q < 8; ++q) {
        float4 t = hp[q];
        hr[4 * q + 0] = t.x; hr[4 * q + 1] = t.y;
        hr[4 * q + 2] = t.z; hr[4 * q + 3] = t.w;
    }

    float agg[HIDDEN];
#pragma unroll
    for (int h = 0; h < HIDDEN; ++h) agg[h] = degf * b2[h];
#pragma unroll
    for (int k = 0; k < HIDDEN; ++k) {
        const float t = hr[k];
#pragma unroll
        for (int h = 0; h < HIDDEN; ++h)
            agg[h] = fmaf(t, W2[k * HIDDEN + h], agg[h]);
    }

    float a[D_NODE];
    const float2* xp = reinterpret_cast<const float2*>(x + (size_t)n * D_NODE);
#pragma unroll
    for (int q = 0; q < 11; ++q) {
        float2 t = xp[q];
        a[2 * q] = t.x; a[2 * q + 1] = t.y;
    }

    float mu = bmu[0], sg = bsig[0], al = bconc[0];
#pragma unroll
    for (int k = 0; k < D_NODE; ++k) {
        const float t = a[k];
        mu = fmaf(t, Wmu[k],   mu);
        sg = fmaf(t, Wsig[k],  sg);
        al = fmaf(t, Wconc[k], al);
    }
#pragma unroll
    for (int k = 0; k < HIDDEN; ++k) {
        const float t = agg[k];
        mu = fmaf(t, Wmu[D_NODE + k],   mu);
        sg = fmaf(t, Wsig[D_NODE + k],  sg);
        al = fmaf(t, Wconc[D_NODE + k], al);
    }

    out[n]               = softplus_f(mu);
    out[N_NODES + n]     = softplus_f(sg);
    out[2 * N_NODES + n] = softplus_f(al);
}

// ---- fallback: round-3 proven fused path ----------------------------------

__global__ __launch_bounds__(256) void edge_mlp_reduce(
    const float* __restrict__ x,
    const int*   __restrict__ edge_index,
    const float* __restrict__ edge_attr,
    const int*   __restrict__ edge_list,
    const float* __restrict__ W1,
    const float* __restrict__ b1,
    const float* __restrict__ W2,
    const float* __restrict__ b2,
    float*       __restrict__ agg)
{
    __shared__ float lmsg[256][33];
    __shared__ int   lsrc[256];
    __shared__ int   lstart[257];
    __shared__ unsigned long long lmask[4];

    const int tid = threadIdx.x;
    const int p = blockIdx.x * 256 + tid;

    const int e   = edge_list[p];
    const int src = edge_index[e];
    const int j   = edge_index[N_EDGES + e];

    const float* __restrict__ xi = x + (size_t)src * D_NODE;
    const float* __restrict__ xj = x + (size_t)j   * D_NODE;
    const float* __restrict__ ep = edge_attr + (size_t)e * D_NODE;

    float hid[HIDDEN];
#pragma unroll
    for (int h = 0; h < HIDDEN; ++h) hid[h] = b1[h];
#pragma unroll
    for (int k = 0; k < D_NODE; ++k) {
        const float t = xi[k];
#pragma unroll
        for (int h = 0; h < HIDDEN; ++h)
            hid[h] = fmaf(t, W1[k * HIDDEN + h], hid[h]);
    }
#pragma unroll
    for (int k = 0; k < D_NODE; ++k) {
        const float t = xj[k];
#pragma unroll
        for (int h = 0; h < HIDDEN; ++h)
            hid[h] = fmaf(t, W1[(D_NODE + k) * HIDDEN + h], hid[h]);
    }
#pragma unroll
    for (int k = 0; k < D_NODE; ++k) {
        const float t = ep[k];
#pragma unroll
        for (int h = 0; h < HIDDEN; ++h)
            hid[h] = fmaf(t, W1[(2 * D_NODE + k) * HIDDEN + h], hid[h]);
    }
#pragma unroll
    for (int h = 0; h < HIDDEN; ++h) hid[h] = fmaxf(hid[h], 0.0f);

    float msg[HIDDEN];
#pragma unroll
    for (int o = 0; o < HIDDEN; ++o) msg[o] = b2[o];
#pragma unroll
    for (int k = 0; k < HIDDEN; ++k) {
        const float t = hid[k];
#pragma unroll
        for (int o = 0; o < HIDDEN; ++o)
            msg[o] = fmaf(t, W2[k * HIDDEN + o], msg[o]);
    }

    lsrc[tid] = src;
#pragma unroll
    for (int o = 0; o < HIDDEN; ++o) lmsg[tid][o] = msg[o];
    __syncthreads();

    const bool head = (tid == 0) || (lsrc[tid] != lsrc[tid - 1]);
    const unsigned long long m = __ballot(head ? 1 : 0);
    const int wv = tid >> 6, lane = tid & 63;
    if (lane == 0) lmask[wv] = m;
    __syncthreads();

    const int nseg = __popcll(lmask[0]) + __popcll(lmask[1]) +
                     __popcll(lmask[2]) + __popcll(lmask[3]);
    if (head) {
        int sid = 0;
        for (int w = 0; w < 4; ++w)
            if (w < wv) sid += __popcll(lmask[w]);
        const unsigned long long below =
            (lane == 0) ? 0ULL : (lmask[wv] & ((1ULL << lane) - 1ULL));
        sid += __popcll(below);
        lstart[sid] = tid;
    }
    if (tid == 0) lstart[nseg] = 256;
    __syncthreads();

    for (int item = tid; item < nseg * HIDDEN; item += 256) {
        const int s = item >> 5;
        const int c = item & 31;
        const int st = lstart[s];
        const int en = lstart[s + 1];
        float sum = 0.0f;
        for (int r = st; r < en; ++r) sum += lmsg[r][c];
        const int node = lsrc[st];
        float* dstp = agg + (size_t)node * HIDDEN + c;
        if (s == 0 || s == nseg - 1) atomicAdd(dstp, sum);
        else *dstp = sum;
    }
}

__global__ __launch_bounds__(256) void node_head_kernel(
    const float* __restrict__ x,
    const float* __restrict__ agg,
    const float* __restrict__ Wmu,  const float* __restrict__ bmu,
    const float* __restrict__ Wsig, const float* __restrict__ bsig,
    const float* __restrict__ Wconc,const float* __restrict__ bconc,
    float*       __restrict__ out)
{
    int n = blockIdx.x * blockDim.x + threadIdx.x;
    if (n >= N_NODES) return;

    float mu = bmu[0], sg = bsig[0], al = bconc[0];

    const float* __restrict__ xp = x + (size_t)n * D_NODE;
#pragma unroll
    for (int k = 0; k < D_NODE; ++k) {
        const float t = xp[k];
        mu = fmaf(t, Wmu[k],   mu);
        sg = fmaf(t, Wsig[k],  sg);
        al = fmaf(t, Wconc[k], al);
    }
    const float* __restrict__ ap = agg + (size_t)n * HIDDEN;
#pragma unroll
    for (int k = 0; k < HIDDEN; ++k) {
        const float t = ap[k];
        mu = fmaf(t, Wmu[D_NODE + k],   mu);
        sg = fmaf(t, Wsig[D_NODE + k],  sg);
        al = fmaf(t, Wconc[D_NODE + k], al);
    }

    out[n]               = softplus_f(mu);
    out[N_NODES + n]     = softplus_f(sg);
    out[2 * N_NODES + n] = softplus_f(al);
}

// ---- launch ---------------------------------------------------------------

extern "C" void kernel_launch(void* const* d_in, const int* in_sizes, int n_in,
                              void* d_out, int out_size, void* d_ws, size_t ws_size,
                              hipStream_t stream) {
    const float* x     = (const float*)d_in[0];
    const int*   ei    = (const int*)  d_in[1];
    const float* ea    = (const float*)d_in[2];
    const float* W1    = (const float*)d_in[3];
    const float* b1    = (const float*)d_in[4];
    const float* W2    = (const float*)d_in[5];
    const float* b2    = (const float*)d_in[6];
    const float* Wmu   = (const float*)d_in[7];
    const float* bmu   = (const float*)d_in[8];
    const float* Wsig  = (const float*)d_in[9];
    const float* bsig  = (const float*)d_in[10];
    const float* Wconc = (const float*)d_in[11];
    const float* bconc = (const float*)d_in[12];

    float* out = (float*)d_out;

    // layout (4B words):
    //   counts[N_PAD] | offsets[N_PAD] | bsums[128] | rank[E] | edge_list[E] |
    //   u[N*32 bf16] | v[N*32 bf16] | H[N*32 f32]      (~52 MB total)
    int* counts    = (int*)d_ws;
    int* offsets   = counts + N_PAD;
    int* bsums     = offsets + N_PAD;
    int* rank      = bsums + 128;
    int* edge_list = rank + N_EDGES;
    unsigned short* u = (unsigned short*)(edge_list + N_EDGES);
    unsigned short* v = u + (size_t)N_NODES * HIDDEN;
    float* H          = (float*)(v + (size_t)N_NODES * HIDDEN);

    const size_t req =
        ((size_t)N_PAD * 2 + 128 + (size_t)N_EDGES * 2) * 4
        + (size_t)N_NODES * HIDDEN * 2 * 2        // u + v (bf16)
        + (size_t)N_NODES * HIDDEN * 4;           // H (f32)

    if (ws_size >= req) {
        (void)hipMemsetAsync(counts, 0, N_PAD * sizeof(int), stream);
        uv_kernel<<<NODE_NB, 256, 0, stream>>>(x, W1, u, v);
        count_rank_kernel<<<EDGE_NB, 256, 0, stream>>>(ei, counts, rank);
        scan_part<<<SCAN_NB, 256, 0, stream>>>(counts, offsets, bsums);
        scan_sums<<<1, 128, 0, stream>>>(bsums);
        scan_add<<<SCAN_NB, 256, 0, stream>>>(offsets, bsums);
        fill_kernel<<<EDGE_NB, 256, 0, stream>>>(ei, offsets, rank, edge_list);

        (void)hipMemsetAsync(H, 0, (size_t)N_NODES * HIDDEN * sizeof(float), stream);
        edge_fused_reduce<<<EDGE_NB, 256, 0, stream>>>(
            ei, ea, edge_list, u, v, W1, b1, H);

        node_out_kernel<<<NODE_NB, 256, 0, stream>>>(
            x, H, counts, W2, b2, Wmu, bmu, Wsig, bsig, Wconc, bconc, out);
    } else {
        // fallback: round-3 proven path
        float* agg_fb = (float*)u;

        (void)hipMemsetAsync(counts, 0, N_PAD * sizeof(int), stream);
        count_rank_kernel<<<EDGE_NB, 256, 0, stream>>>(ei, counts, rank);
        scan_part<<<SCAN_NB, 256, 0, stream>>>(counts, offsets, bsums);
        scan_sums<<<1, 128, 0, stream>>>(bsums);
        scan_add<<<SCAN_NB, 256, 0, stream>>>(offsets, bsums);
        fill_kernel<<<EDGE_NB, 256, 0, stream>>>(ei, offsets, rank, edge_list);
        (void)hipMemsetAsync(agg_fb, 0, (size_t)N_NODES * HIDDEN * sizeof(float), stream);
        edge_mlp_reduce<<<EDGE_NB, 256, 0, stream>>>(
            x, ei, ea, edge_list, W1, b1, W2, b2, agg_fb);
        node_head_kernel<<<NODE_NB, 256, 0, stream>>>(
            x, agg_fb, Wmu, bmu, Wsig, bsig, Wconc, bconc, out);
    }
}